// Round 7
// baseline (120.807 us; speedup 1.0000x reference)
//
#include <hip/hip_runtime.h>

// LeakyIntegrator: T=64 scan, independent per (c,h,w) element.
// m_t = r ? img : (a ? m + lam*cov*(img - m) : m)        [algebraic lerp form]
// c_t = r ? cov : (a ? clip(c+cov,0,1) : c),   reset[0] forced true.
//
// FINAL (R4 config — best of the {width}x{store} matrix):
//   float2/thread, 32 waves/CU (8/SIMD), depth-2 prefetch, full unroll,
//   nt LOADS on img (don't evict cov from L2), PLAIN stores.
// Matrix (dur_us): f4+nt 109.2 | f4+plain 114.4 | f2+nt 107.5 | f2+plain 95.1.
// Mechanism: plain stores need full occupancy to hide L2-write backpressure;
// nt stores bypass L2 and drain inefficiently regardless of occupancy.
// 545 MB @ 95.1 us = 5.73 TB/s = 91% of measured 6.29 TB/s copy ceiling.

#define LAM 0.2f
#define T_STEPS 64
#define C_CH 64
#define H_DIM 128
#define W_DIM 128
#define HW (H_DIM * W_DIM)            // 16384
#define CHW (C_CH * HW)               // 1048576
#define MAPS_SIZE ((size_t)T_STEPS * CHW)
#define PFD 2                         // prefetch depth (depth-4 regressed: R2)

typedef float f32x2 __attribute__((ext_vector_type(2)));

// T == wave width: lane t loads mask[t], ballot packs the 64 bools.
// add_mask is all-True by construction -> first 4 bytes disambiguate
// int32 bools (0x00000001) vs byte bools (0x01010101).
__device__ __forceinline__ void load_masks_ballot(const void* add_p, const void* reset_p,
                                                  unsigned long long& abits,
                                                  unsigned long long& rbits) {
    const int lane = threadIdx.x & 63;
    const unsigned int w0 = *(const unsigned int*)add_p;
    int av, rv;
    if (w0 == 1u) {  // int32 bools
        av = ((const int*)add_p)[lane];
        rv = ((const int*)reset_p)[lane];
    } else {         // byte bools
        av = ((const unsigned char*)add_p)[lane];
        rv = ((const unsigned char*)reset_p)[lane];
    }
    abits = __ballot(av != 0);
    rbits = __ballot(rv != 0) | 1ull;   // step 0 always resets
}

__global__ __launch_bounds__(256, 8) void li_fused_kernel(
        const float* __restrict__ img, const float* __restrict__ cov,
        const void* __restrict__ addm, const void* __restrict__ resetm,
        float* __restrict__ out) {
    const int tid  = blockIdx.x * 256 + threadIdx.x;   // 0 .. CHW/2-1
    const int pix2 = tid & (HW / 2 - 1);               // 0..8191
    const int c    = tid >> 13;                        // 0..63
    const int base    = c * HW + pix2 * 2;
    const int covbase = pix2 * 2;
    const bool do_cov = (c == 0);                      // blocks 0..31, block-uniform

    unsigned long long abits, rbits;
    load_masks_ballot(addm, resetm, abits, rbits);

    const float* ip  = img + base;
    const float* cp  = cov + covbase;
    float*       mop = out + base;
    float*       cop = out + MAPS_SIZE + covbase;

    // depth-2 prefetch; all indices compile-time after full unroll.
    f32x2 imb[PFD], cvb[PFD];
    #pragma unroll
    for (int t = 0; t < PFD; ++t) {
        imb[t] = __builtin_nontemporal_load((const f32x2*)(ip + (size_t)t * CHW));
        cvb[t] = *(const f32x2*)(cp + (size_t)t * HW);
    }

    f32x2 m  = (f32x2)(0.f);
    f32x2 cc = (f32x2)(0.f);

    #pragma unroll
    for (int t = 0; t < T_STEPS; ++t) {
        const f32x2 im = imb[t % PFD];
        const f32x2 cv = cvb[t % PFD];
        if (t + PFD < T_STEPS) {
            imb[t % PFD] = __builtin_nontemporal_load((const f32x2*)(ip + (size_t)(t + PFD) * CHW));
            cvb[t % PFD] = *(const f32x2*)(cp + (size_t)(t + PFD) * HW);
        }
        const bool r = (rbits >> t) & 1ull;
        const bool a = (abits >> t) & 1ull;

        // m_upd = (1-lam)m + lam*img*cov + lam*m*(1-cov)  ==  m + lam*cov*(img-m)
        f32x2 mu;
        mu.x = fmaf(LAM * cv.x, im.x - m.x, m.x);
        mu.y = fmaf(LAM * cv.y, im.y - m.y, m.y);

        m.x = r ? im.x : (a ? mu.x : m.x);
        m.y = r ? im.y : (a ? mu.y : m.y);

        *(f32x2*)(mop + (size_t)t * CHW) = m;   // plain store: L2 write-coalesce

        if (do_cov) {
            f32x2 cu;
            cu.x = fminf(fmaxf(cc.x + cv.x, 0.f), 1.f);
            cu.y = fminf(fmaxf(cc.y + cv.y, 0.f), 1.f);
            cc.x = r ? cv.x : (a ? cu.x : cc.x);
            cc.y = r ? cv.y : (a ? cu.y : cc.y);
            *(f32x2*)(cop + (size_t)t * HW) = cc;
        }
    }
}

extern "C" void kernel_launch(void* const* d_in, const int* in_sizes, int n_in,
                              void* d_out, int out_size, void* d_ws, size_t ws_size,
                              hipStream_t stream) {
    const float* img    = (const float*)d_in[0];
    const float* cov    = (const float*)d_in[1];
    const void*  addm   = d_in[2];
    const void*  resetm = d_in[3];
    float* out = (float*)d_out;

    li_fused_kernel<<<(CHW / 2) / 256, 256, 0, stream>>>(img, cov, addm, resetm, out);
}

// Round 8
// 106.693 us; speedup vs baseline: 1.1323x; 1.1323x over previous
//
#include <hip/hip_runtime.h>

// LeakyIntegrator: T=64 scan, independent per (c,h,w) element.
// m_t = r ? img : (a ? m + lam*cov*(img - m) : m)        [algebraic lerp form]
// c_t = r ? cov : (a ? clip(c+cov,0,1) : c),   reset[0] forced true.
//
// R7: channel-grouped blocks to make cov reuse structural instead of
// allocation-luck. Block = 4 channels x 128 pixels (one channel per wave,
// f32x2 per thread). All 4 waves share the same 512B cov slice per t (L1
// broadcast); distinct-block touches per cov line drop 64 -> 16. cgrp is the
// fast-varying block index so the 16 readers of a pixel-group dispatch
// together. Keeps R4 config: 32 waves/CU, depth-2 prefetch, full unroll,
// nt img loads (protect cov in L2), plain stores.
// Evidence: identical R4 binary ran 95.1 then 120.8 us; delta == cov
// re-fetch from HBM (~180 MB) when write-allocate stream evicts cov.

#define LAM 0.2f
#define T_STEPS 64
#define C_CH 64
#define H_DIM 128
#define W_DIM 128
#define HW (H_DIM * W_DIM)            // 16384
#define CHW (C_CH * HW)               // 1048576
#define MAPS_SIZE ((size_t)T_STEPS * CHW)
#define PFD 2                         // prefetch depth (depth-4 regressed: R2)
#define CPERBLK 4                     // channels per block (1 per wave)
#define PIXPERBLK 128                 // pixels per block (64 lanes x f32x2)

typedef float f32x2 __attribute__((ext_vector_type(2)));

// T == wave width: lane t loads mask[t], ballot packs the 64 bools.
// add_mask is all-True by construction -> first 4 bytes disambiguate
// int32 bools (0x00000001) vs byte bools (0x01010101).
__device__ __forceinline__ void load_masks_ballot(const void* add_p, const void* reset_p,
                                                  unsigned long long& abits,
                                                  unsigned long long& rbits) {
    const int lane = threadIdx.x & 63;
    const unsigned int w0 = *(const unsigned int*)add_p;
    int av, rv;
    if (w0 == 1u) {  // int32 bools
        av = ((const int*)add_p)[lane];
        rv = ((const int*)reset_p)[lane];
    } else {         // byte bools
        av = ((const unsigned char*)add_p)[lane];
        rv = ((const unsigned char*)reset_p)[lane];
    }
    abits = __ballot(av != 0);
    rbits = __ballot(rv != 0) | 1ull;   // step 0 always resets
}

__global__ __launch_bounds__(256, 8) void li_fused_kernel(
        const float* __restrict__ img, const float* __restrict__ cov,
        const void* __restrict__ addm, const void* __restrict__ resetm,
        float* __restrict__ out) {
    const int cgrp   = blockIdx.x & (C_CH / CPERBLK - 1);   // 0..15, fast-varying
    const int pixgrp = blockIdx.x >> 4;                     // 0..127
    const int w      = threadIdx.x >> 6;                    // wave 0..3
    const int lane   = threadIdx.x & 63;
    const int c      = cgrp * CPERBLK + w;
    const int pix    = pixgrp * PIXPERBLK + lane * 2;
    const int base    = c * HW + pix;
    const int covbase = pix;
    const bool do_cov = (cgrp == 0) && (w == 0);            // wave-uniform

    unsigned long long abits, rbits;
    load_masks_ballot(addm, resetm, abits, rbits);

    const float* ip  = img + base;
    const float* cp  = cov + covbase;
    float*       mop = out + base;
    float*       cop = out + MAPS_SIZE + covbase;

    // depth-2 prefetch; all indices compile-time after full unroll.
    f32x2 imb[PFD], cvb[PFD];
    #pragma unroll
    for (int t = 0; t < PFD; ++t) {
        imb[t] = __builtin_nontemporal_load((const f32x2*)(ip + (size_t)t * CHW));
        cvb[t] = *(const f32x2*)(cp + (size_t)t * HW);
    }

    f32x2 m  = (f32x2)(0.f);
    f32x2 cc = (f32x2)(0.f);

    #pragma unroll
    for (int t = 0; t < T_STEPS; ++t) {
        const f32x2 im = imb[t % PFD];
        const f32x2 cv = cvb[t % PFD];
        if (t + PFD < T_STEPS) {
            imb[t % PFD] = __builtin_nontemporal_load((const f32x2*)(ip + (size_t)(t + PFD) * CHW));
            cvb[t % PFD] = *(const f32x2*)(cp + (size_t)(t + PFD) * HW);
        }
        const bool r = (rbits >> t) & 1ull;
        const bool a = (abits >> t) & 1ull;

        // m_upd = (1-lam)m + lam*img*cov + lam*m*(1-cov)  ==  m + lam*cov*(img-m)
        f32x2 mu;
        mu.x = fmaf(LAM * cv.x, im.x - m.x, m.x);
        mu.y = fmaf(LAM * cv.y, im.y - m.y, m.y);

        m.x = r ? im.x : (a ? mu.x : m.x);
        m.y = r ? im.y : (a ? mu.y : m.y);

        *(f32x2*)(mop + (size_t)t * CHW) = m;   // plain store: L2 write-coalesce

        if (do_cov) {
            f32x2 cu;
            cu.x = fminf(fmaxf(cc.x + cv.x, 0.f), 1.f);
            cu.y = fminf(fmaxf(cc.y + cv.y, 0.f), 1.f);
            cc.x = r ? cv.x : (a ? cu.x : cc.x);
            cc.y = r ? cv.y : (a ? cu.y : cc.y);
            *(f32x2*)(cop + (size_t)t * HW) = cc;
        }
    }
}

extern "C" void kernel_launch(void* const* d_in, const int* in_sizes, int n_in,
                              void* d_out, int out_size, void* d_ws, size_t ws_size,
                              hipStream_t stream) {
    const float* img    = (const float*)d_in[0];
    const float* cov    = (const float*)d_in[1];
    const void*  addm   = d_in[2];
    const void*  resetm = d_in[3];
    float* out = (float*)d_out;

    // grid: (HW/PIXPERBLK) pixel-groups x (C_CH/CPERBLK) channel-groups
    li_fused_kernel<<<(HW / PIXPERBLK) * (C_CH / CPERBLK), 256, 0, stream>>>(
        img, cov, addm, resetm, out);
}

// Round 9
// 95.873 us; speedup vs baseline: 1.2601x; 1.1129x over previous
//
#include <hip/hip_runtime.h>

// LeakyIntegrator: T=64 scan, independent per (c,h,w) element.
// m_t = r ? img : (a ? m + lam*cov*(img - m) : m)        [algebraic lerp form]
// c_t = r ? cov : (a ? clip(c+cov,0,1) : c),   reset[0] forced true.
//
// R8: R7 + XCD co-location of cov readers. Block = 4 channels x 128 pixels
// (one channel per wave, f32x2/thread). Decode blockIdx = cgrp*128 + pixgrp
// (pixgrp FAST): the 16 reader-blocks of a pixel-group are b ≡ pixgrp (mod 8)
// -> same XCD under round-robin dispatch, so each cov line is HBM-fetched
// once and L2-resident (per-XCD cov stripe = 512 KiB << 4 MiB L2).
// R7 (cgrp fast) spread readers over all 8 XCDs -> x8 L2 replication and
// allocation-luck residency: 95.1/106.7/120.8 us spread on ~identical code.
// Config from R4 matrix: 32 waves/CU, depth-2 prefetch, full unroll,
// nt img loads (no L2 pollution), plain stores (L2 write-coalesce).

#define LAM 0.2f
#define T_STEPS 64
#define C_CH 64
#define H_DIM 128
#define W_DIM 128
#define HW (H_DIM * W_DIM)            // 16384
#define CHW (C_CH * HW)               // 1048576
#define MAPS_SIZE ((size_t)T_STEPS * CHW)
#define PFD 2                         // prefetch depth (depth-4 regressed: R2)
#define CPERBLK 4                     // channels per block (1 per wave)
#define PIXPERBLK 128                 // pixels per block (64 lanes x f32x2)

typedef float f32x2 __attribute__((ext_vector_type(2)));

// T == wave width: lane t loads mask[t], ballot packs the 64 bools.
// add_mask is all-True by construction -> first 4 bytes disambiguate
// int32 bools (0x00000001) vs byte bools (0x01010101).
__device__ __forceinline__ void load_masks_ballot(const void* add_p, const void* reset_p,
                                                  unsigned long long& abits,
                                                  unsigned long long& rbits) {
    const int lane = threadIdx.x & 63;
    const unsigned int w0 = *(const unsigned int*)add_p;
    int av, rv;
    if (w0 == 1u) {  // int32 bools
        av = ((const int*)add_p)[lane];
        rv = ((const int*)reset_p)[lane];
    } else {         // byte bools
        av = ((const unsigned char*)add_p)[lane];
        rv = ((const unsigned char*)reset_p)[lane];
    }
    abits = __ballot(av != 0);
    rbits = __ballot(rv != 0) | 1ull;   // step 0 always resets
}

__global__ __launch_bounds__(256, 8) void li_fused_kernel(
        const float* __restrict__ img, const float* __restrict__ cov,
        const void* __restrict__ addm, const void* __restrict__ resetm,
        float* __restrict__ out) {
    const int pixgrp = blockIdx.x & (HW / PIXPERBLK - 1);   // 0..127, FAST
    const int cgrp   = blockIdx.x >> 7;                     // 0..15, slow
    const int w      = threadIdx.x >> 6;                    // wave 0..3
    const int lane   = threadIdx.x & 63;
    const int c      = cgrp * CPERBLK + w;
    const int pix    = pixgrp * PIXPERBLK + lane * 2;
    const int base    = c * HW + pix;
    const int covbase = pix;
    const bool do_cov = (cgrp == 0) && (w == 0);            // wave-uniform

    unsigned long long abits, rbits;
    load_masks_ballot(addm, resetm, abits, rbits);

    const float* ip  = img + base;
    const float* cp  = cov + covbase;
    float*       mop = out + base;
    float*       cop = out + MAPS_SIZE + covbase;

    // depth-2 prefetch; all indices compile-time after full unroll.
    f32x2 imb[PFD], cvb[PFD];
    #pragma unroll
    for (int t = 0; t < PFD; ++t) {
        imb[t] = __builtin_nontemporal_load((const f32x2*)(ip + (size_t)t * CHW));
        cvb[t] = *(const f32x2*)(cp + (size_t)t * HW);
    }

    f32x2 m  = (f32x2)(0.f);
    f32x2 cc = (f32x2)(0.f);

    #pragma unroll
    for (int t = 0; t < T_STEPS; ++t) {
        const f32x2 im = imb[t % PFD];
        const f32x2 cv = cvb[t % PFD];
        if (t + PFD < T_STEPS) {
            imb[t % PFD] = __builtin_nontemporal_load((const f32x2*)(ip + (size_t)(t + PFD) * CHW));
            cvb[t % PFD] = *(const f32x2*)(cp + (size_t)(t + PFD) * HW);
        }
        const bool r = (rbits >> t) & 1ull;
        const bool a = (abits >> t) & 1ull;

        // m_upd = (1-lam)m + lam*img*cov + lam*m*(1-cov)  ==  m + lam*cov*(img-m)
        f32x2 mu;
        mu.x = fmaf(LAM * cv.x, im.x - m.x, m.x);
        mu.y = fmaf(LAM * cv.y, im.y - m.y, m.y);

        m.x = r ? im.x : (a ? mu.x : m.x);
        m.y = r ? im.y : (a ? mu.y : m.y);

        *(f32x2*)(mop + (size_t)t * CHW) = m;   // plain store: L2 write-coalesce

        if (do_cov) {
            f32x2 cu;
            cu.x = fminf(fmaxf(cc.x + cv.x, 0.f), 1.f);
            cu.y = fminf(fmaxf(cc.y + cv.y, 0.f), 1.f);
            cc.x = r ? cv.x : (a ? cu.x : cc.x);
            cc.y = r ? cv.y : (a ? cu.y : cc.y);
            *(f32x2*)(cop + (size_t)t * HW) = cc;
        }
    }
}

extern "C" void kernel_launch(void* const* d_in, const int* in_sizes, int n_in,
                              void* d_out, int out_size, void* d_ws, size_t ws_size,
                              hipStream_t stream) {
    const float* img    = (const float*)d_in[0];
    const float* cov    = (const float*)d_in[1];
    const void*  addm   = d_in[2];
    const void*  resetm = d_in[3];
    float* out = (float*)d_out;

    // grid: 16 channel-groups (slow) x 128 pixel-groups (fast)
    li_fused_kernel<<<(C_CH / CPERBLK) * (HW / PIXPERBLK), 256, 0, stream>>>(
        img, cov, addm, resetm, out);
}